// Round 2
// 488.929 us; speedup vs baseline: 1.0223x; 1.0223x over previous
//
#include <hip/hip_runtime.h>

#define N 8192
#define T 64
#define TILES (N / T)              // 128
#define SUP 8                      // tiles per super-tile side (512 floats = 2KB/row span)
#define NSUP (TILES / SUP)         // 16 super-stripes
#define PPB 4                      // tile-pairs per block
#define NBLOCKS 2064               // 120 off-diag supers*16 blocks + 16 diag supers*9 blocks
#define LDS_STRIDE 65              // +1 pad: transposed reads are 2-way (free per m136)
#define BLOCK 512

// native vector type for __builtin_nontemporal_store (HIP float4 class is rejected)
typedef float nfloat4 __attribute__((ext_vector_type(4)));

// Map block -> PPB tile-pairs, grouped into 8x8-tile super-tiles so that
// concurrently-resident blocks touch 2KB-contiguous row spans (DRAM page dense)
// on BOTH the (bi,bj) side and the transposed (bj,bi) side.
// blocks before super-stripe BI: 9*BI + 16*sum_{k<BI}(15-k) = 257*BI - 8*BI*BI
__device__ inline void decode_block(int b, int bis[PPB], int bjs[PPB]) {
    int BI = 0;
    #pragma unroll 1
    while (BI < NSUP - 1) {
        int nb = BI + 1;
        if (257 * nb - 8 * nb * nb <= b) BI = nb; else break;
    }
    int rem = b - (257 * BI - 8 * BI * BI);
    if (rem < 9) {
        // diagonal super-tile: 36 triangular 8x8 pairs; chunk rem covers l=4*rem..+3
        #pragma unroll
        for (int u = 0; u < PPB; u++) {
            int l = 4 * rem + u;
            int i = 0;
            #pragma unroll 1
            while ((i + 1) * 8 - (i + 1) * i / 2 <= l) i++;
            int j = i + (l - (i * 8 - i * (i - 1) / 2));
            bis[u] = BI * SUP + i;
            bjs[u] = BI * SUP + j;
        }
    } else {
        // off-diagonal super (BI, BI+d): 64 pairs, 16 chunks of 4 consecutive bj
        int r2 = rem - 9;
        int d = (r2 >> 4) + 1;
        int q = r2 & 15;
        int i = q >> 1;
        int j0 = (q & 1) * 4;
        #pragma unroll
        for (int u = 0; u < PPB; u++) {
            bis[u] = BI * SUP + i;                 // bi constant within block
            bjs[u] = (BI + d) * SUP + j0 + u;      // 4 consecutive bj tiles
        }
    }
}

// Pass 1: rowsum[i] = sum_j max(adj[i][j], adj[j][i]), diagonal forced to 1.
// Register double-buffered staging: pair k+1's global loads are in flight
// during pair k's compute. bi-side row sums accumulate across same-bi pairs.
__global__ __launch_bounds__(BLOCK) void k_rowsum(const float* __restrict__ adj,
                                                  float* __restrict__ rowsum) {
    __shared__ float ldsA[T * LDS_STRIDE];
    __shared__ float ldsB[T * LDS_STRIDE];
    __shared__ float red[BLOCK];
    int bis[PPB], bjs[PPB];
    decode_block((int)blockIdx.x, bis, bjs);

    int t = threadIdx.x;
    int c4 = t & 15;         // float4 column 0..15
    int r0 = t >> 4;         // row 0..31 (and +32)
    int lane = t & 63;
    int w = t >> 6;          // 0..7

    // prefetch pair 0 into registers
    float4 nA0, nA1, nB0, nB1;
    {
        const float* pa = adj + (size_t)(bis[0] * T + r0) * N + bjs[0] * T + c4 * 4;
        nA0 = *(const float4*)pa;
        nA1 = *(const float4*)(pa + (size_t)32 * N);
        const float* pb = adj + (size_t)(bjs[0] * T + r0) * N + bis[0] * T + c4 * 4;
        nB0 = *(const float4*)pb;
        nB1 = *(const float4*)(pb + (size_t)32 * N);
    }

    float accA = 0.0f;
    #pragma unroll
    for (int k = 0; k < PPB; k++) {
        int bi = bis[k], bj = bjs[k];
        if (k > 0) __syncthreads();          // LDS consumed by previous pair
        {
            float* d0 = ldsA + r0 * LDS_STRIDE + c4 * 4;
            d0[0] = nA0.x; d0[1] = nA0.y; d0[2] = nA0.z; d0[3] = nA0.w;
            float* d1 = ldsA + (r0 + 32) * LDS_STRIDE + c4 * 4;
            d1[0] = nA1.x; d1[1] = nA1.y; d1[2] = nA1.z; d1[3] = nA1.w;
            float* e0 = ldsB + r0 * LDS_STRIDE + c4 * 4;
            e0[0] = nB0.x; e0[1] = nB0.y; e0[2] = nB0.z; e0[3] = nB0.w;
            float* e1 = ldsB + (r0 + 32) * LDS_STRIDE + c4 * 4;
            e1[0] = nB1.x; e1[1] = nB1.y; e1[2] = nB1.z; e1[3] = nB1.w;
        }
        if (k + 1 < PPB) {                   // issue next pair's loads now
            const float* pa = adj + (size_t)(bis[k + 1] * T + r0) * N + bjs[k + 1] * T + c4 * 4;
            nA0 = *(const float4*)pa;
            nA1 = *(const float4*)(pa + (size_t)32 * N);
            const float* pb = adj + (size_t)(bjs[k + 1] * T + r0) * N + bis[k + 1] * T + c4 * 4;
            nB0 = *(const float4*)pb;
            nB1 = *(const float4*)(pb + (size_t)32 * N);
        }
        __syncthreads();

        // bj-side column sums (skip for diagonal tiles: fully counted on bi side)
        if (bi != bj) {
            float acc2 = 0.0f;
            #pragma unroll
            for (int kk = 0; kk < 8; kk++) {
                int r = w * 8 + kk;
                acc2 += fmaxf(ldsA[r * LDS_STRIDE + lane], ldsB[lane * LDS_STRIDE + r]);
            }
            red[t] = acc2;
            __syncthreads();
            if (t < 64) {
                float s = 0.0f;
                #pragma unroll
                for (int w2 = 0; w2 < 8; w2++) s += red[w2 * 64 + t];
                atomicAdd(&rowsum[bj * T + t], s);
            }
        }

        // bi-side row sums: thread owns row=lane, cols w*8..w*8+7; accumulate across pairs
        #pragma unroll
        for (int kk = 0; kk < 8; kk++) {
            int c = w * 8 + kk;
            float m = fmaxf(ldsA[lane * LDS_STRIDE + c], ldsB[c * LDS_STRIDE + lane]);
            if (bi == bj && lane == c) m = 1.0f;   // self-loop
            accA += m;
        }
        bool flush = (k == PPB - 1) || (bis[k + 1] != bi);
        if (flush) {
            __syncthreads();                 // also protects red[] from bj-side readers
            red[t] = accA;
            __syncthreads();
            if (t < 64) {
                float s = 0.0f;
                #pragma unroll
                for (int w2 = 0; w2 < 8; w2++) s += red[w2 * 64 + t];
                atomicAdd(&rowsum[bi * T + t], s);
            }
            accA = 0.0f;
        }
    }
}

// Pass 2: out[i][j] = max'(i,j) * rsqrt(rowsum[i]) * rsqrt(rowsum[j])
// Same super-tile schedule + register double-buffering; non-temporal stores
// keep the 256MiB adj resident in L3 for this pass's reads.
__global__ __launch_bounds__(BLOCK) void k_scale(const float* __restrict__ adj,
                                                 const float* __restrict__ rowsum,
                                                 float* __restrict__ out) {
    __shared__ float ldsA[T * LDS_STRIDE];
    __shared__ float ldsB[T * LDS_STRIDE];
    __shared__ float dA[T];
    __shared__ float dB[T];
    int bis[PPB], bjs[PPB];
    decode_block((int)blockIdx.x, bis, bjs);

    int t = threadIdx.x;
    int c4 = t & 15;
    int r0 = t >> 4;         // 0..31

    // prefetch all rowsum slices for this block (tiny, L2/L3-hot)
    float rA[PPB], rB[PPB];
    #pragma unroll
    for (int u = 0; u < PPB; u++) {
        if (t < 64)       rA[u] = rowsum[bis[u] * T + t];
        else if (t < 128) rB[u] = rowsum[bjs[u] * T + (t - 64)];
    }

    // prefetch pair 0 tiles
    float4 nA0, nA1, nB0, nB1;
    {
        const float* pa = adj + (size_t)(bis[0] * T + r0) * N + bjs[0] * T + c4 * 4;
        nA0 = *(const float4*)pa;
        nA1 = *(const float4*)(pa + (size_t)32 * N);
        const float* pb = adj + (size_t)(bjs[0] * T + r0) * N + bis[0] * T + c4 * 4;
        nB0 = *(const float4*)pb;
        nB1 = *(const float4*)(pb + (size_t)32 * N);
    }

    #pragma unroll
    for (int k = 0; k < PPB; k++) {
        int bi = bis[k], bj = bjs[k];
        if (k > 0) __syncthreads();
        {
            float* d0 = ldsA + r0 * LDS_STRIDE + c4 * 4;
            d0[0] = nA0.x; d0[1] = nA0.y; d0[2] = nA0.z; d0[3] = nA0.w;
            float* d1 = ldsA + (r0 + 32) * LDS_STRIDE + c4 * 4;
            d1[0] = nA1.x; d1[1] = nA1.y; d1[2] = nA1.z; d1[3] = nA1.w;
            float* e0 = ldsB + r0 * LDS_STRIDE + c4 * 4;
            e0[0] = nB0.x; e0[1] = nB0.y; e0[2] = nB0.z; e0[3] = nB0.w;
            float* e1 = ldsB + (r0 + 32) * LDS_STRIDE + c4 * 4;
            e1[0] = nB1.x; e1[1] = nB1.y; e1[2] = nB1.z; e1[3] = nB1.w;
        }
        if (t < 64)       dA[t]      = rsqrtf(rA[k]);
        else if (t < 128) dB[t - 64] = rsqrtf(rB[k]);
        if (k + 1 < PPB) {
            const float* pa = adj + (size_t)(bis[k + 1] * T + r0) * N + bjs[k + 1] * T + c4 * 4;
            nA0 = *(const float4*)pa;
            nA1 = *(const float4*)(pa + (size_t)32 * N);
            const float* pb = adj + (size_t)(bjs[k + 1] * T + r0) * N + bis[k + 1] * T + c4 * 4;
            nB0 = *(const float4*)pb;
            nB1 = *(const float4*)(pb + (size_t)32 * N);
        }
        __syncthreads();

        // Upper tile: rows bi*T+rr, cols bj*T+cc — coalesced float4 nt-stores
        #pragma unroll
        for (int rr = r0; rr < T; rr += 32) {
            nfloat4 v;
            #pragma unroll
            for (int kk = 0; kk < 4; kk++) {
                int cc = c4 * 4 + kk;
                float m = fmaxf(ldsA[rr * LDS_STRIDE + cc], ldsB[cc * LDS_STRIDE + rr]);
                if (bi == bj && rr == cc) m = 1.0f;
                v[kk] = m * dA[rr] * dB[cc];
            }
            __builtin_nontemporal_store(v, (nfloat4*)(out + (size_t)(bi * T + rr) * N + bj * T + c4 * 4));
        }
        // Mirror tile: rows bj*T+rr, cols bi*T+cc
        if (bi != bj) {
            #pragma unroll
            for (int rr = r0; rr < T; rr += 32) {
                nfloat4 v;
                #pragma unroll
                for (int kk = 0; kk < 4; kk++) {
                    int cc = c4 * 4 + kk;
                    float m = fmaxf(ldsB[rr * LDS_STRIDE + cc], ldsA[cc * LDS_STRIDE + rr]);
                    v[kk] = m * dB[rr] * dA[cc];
                }
                __builtin_nontemporal_store(v, (nfloat4*)(out + (size_t)(bj * T + rr) * N + bi * T + c4 * 4));
            }
        }
    }
}

extern "C" void kernel_launch(void* const* d_in, const int* in_sizes, int n_in,
                              void* d_out, int out_size, void* d_ws, size_t ws_size,
                              hipStream_t stream) {
    const float* adj = (const float*)d_in[0];
    float* out = (float*)d_out;
    float* rowsum = (float*)d_ws;   // N floats of scratch

    (void)hipMemsetAsync(rowsum, 0, N * sizeof(float), stream);
    k_rowsum<<<NBLOCKS, BLOCK, 0, stream>>>(adj, rowsum);
    k_scale<<<NBLOCKS, BLOCK, 0, stream>>>(adj, rowsum, out);
}